// Round 1
// 475.107 us; speedup vs baseline: 1.0133x; 1.0133x over previous
//
#include <hip/hip_runtime.h>
#include <hip/hip_bf16.h>
#include <hip/hip_fp16.h>

// GCN autoencoder, R6:
//   memset(cnt) -> fused1{gemm1(x@W1->bf16 h1) || fill(count+bucket)} ->
//   agg1(gather, coef on-the-fly, +b1, relu -> bf16 hrelu) ->
//   gemm2(bf16 @ W2 -> bf16 h2) -> agg2(-> fp32 z) -> gemm3(z@Wd+bd -> x_recon)
//
// R5 post-mortem: fused1 160us with WRITE_SIZE=122MB vs a true write footprint
// of ~32MB. Diagnosis: bucket[d*CAP+r] scatter writes concentrate on line 0 of
// each 256B row -> 64B lines at 256B stride -> only 1/4 of L2 sets usable ->
// the ~6-12MB active line set thrashes, each line cycling through HBM multiple
// times (write-allocate fetch + writeback). The cnt atomics queue behind this
// churn in the same TCC pipes.
// R6: transpose bucket to rank-major [CAP][N] (bucket[r*N+d]). Rank-r writes
// land in a dense, set-uniform 400KB plane; ranks 0..15 carry ~95% of edges ->
// ~16 writes coalesce per line before writeback. agg_k reads become
// bucket[(j+q)*N+n]: same line shared by 16 consecutive nodes -> same ~6.4MB
// read traffic as row-major. Predicted: fused1 WRITE 122->~33MB, dur 160->~100us.

#define TPB 256
#define CAP 64

typedef float v2f __attribute__((ext_vector_type(2)));

// ---------------- helpers ----------------

__device__ __forceinline__ unsigned short f2bf(float f) {
    unsigned u = __float_as_uint(f);
    unsigned r = u + 0x7fffu + ((u >> 16) & 1u);  // RNE
    return (unsigned short)(r >> 16);
}
__device__ __forceinline__ float bf_lo(unsigned u) { return __uint_as_float(u << 16); }
__device__ __forceinline__ float bf_hi(unsigned u) { return __uint_as_float(u & 0xffff0000u); }

// ---------------- GEMM body: out[N,C] = A[N,K] @ W[K,C] (+bias) ----------------
// 128-row block tile, 256 threads, TM=8 x TN per thread.
// W staged in LDS in BK=32 chunks (16KB max) to keep occupancy for co-scheduled
// latency-bound blocks. INBF: A is bf16 packed. OUTBF: emit bf16 packed.

template <int K, int C, int TN, bool BIAS, bool INBF, bool OUTBF>
__device__ __forceinline__ void gemm_body(const void* __restrict__ Ap,
                                          const float* __restrict__ W,
                                          const float* __restrict__ bias,
                                          void* __restrict__ outp, int N, int bid,
                                          float* __restrict__ Ws) {
    constexpr int BM  = 128;
    constexpr int TM  = 8;
    constexpr int BK  = 32;
    constexpr int NCT = C / TN;
    static_assert(NCT * (BM / TM) == TPB, "thread layout");

    int tid = threadIdx.x;
    int tc = tid % NCT;
    int tr = tid / NCT;
    int c0 = tc * TN;
    int r0 = bid * BM + tr * TM;

    float acc[TM][TN] = {};

    for (int k0 = 0; k0 < K; k0 += BK) {
        __syncthreads();
        for (int i = tid * 4; i < BK * C; i += TPB * 4)
            *(float4*)&Ws[i] = *(const float4*)&W[k0 * C + i];
        __syncthreads();

        for (int k = 0; k < BK; k += 4) {
            float4 a[TM];
            uint2  au[TM];
#pragma unroll
            for (int i = 0; i < TM; ++i) {
                int r = r0 + i;
                if (r >= N) r = N - 1;
                if (INBF)
                    au[i] = *(const uint2*)((const unsigned short*)Ap + (size_t)r * K + k0 + k);
                else
                    a[i] = *(const float4*)((const float*)Ap + (size_t)r * K + k0 + k);
            }
#pragma unroll
            for (int kk = 0; kk < 4; ++kk) {
                float w[TN];
#pragma unroll
                for (int j = 0; j < TN; j += 4)
                    *(float4*)&w[j] = *(const float4*)&Ws[(k + kk) * C + c0 + j];
#pragma unroll
                for (int i = 0; i < TM; ++i) {
                    float av;
                    if (INBF) {
                        unsigned uu = (kk < 2) ? au[i].x : au[i].y;
                        av = (kk & 1) ? bf_hi(uu) : bf_lo(uu);
                    } else {
                        av = ((const float*)&a[i])[kk];
                    }
#pragma unroll
                    for (int j = 0; j < TN; ++j) acc[i][j] += av * w[j];
                }
            }
        }
    }

#pragma unroll
    for (int i = 0; i < TM; ++i) {
        int r = r0 + i;
        if (r >= N) continue;
        if (BIAS) {
#pragma unroll
            for (int j = 0; j < TN; ++j) acc[i][j] += bias[c0 + j];
        }
        if (OUTBF) {
            unsigned short* ob = (unsigned short*)outp + (size_t)r * C + c0;
            unsigned pk[TN / 2];
#pragma unroll
            for (int j = 0; j < TN; j += 2)
                pk[j / 2] = (unsigned)f2bf(acc[i][j]) | ((unsigned)f2bf(acc[i][j + 1]) << 16);
            if (TN == 8)      *(uint4*)ob = *(uint4*)pk;
            else if (TN == 4) *(uint2*)ob = *(uint2*)pk;
        } else {
            float* of = (float*)outp + (size_t)r * C + c0;
#pragma unroll
            for (int j = 0; j < TN; j += 4)
                *(float4*)&of[j] = *(float4*)&acc[i][j];
        }
    }
}

// standalone GEMM kernel (layers 2, 3)
template <int K, int C, int TN, bool BIAS, bool INBF, bool OUTBF>
__global__ __launch_bounds__(TPB) void gemm_k(const void* __restrict__ Ap,
                                              const float* __restrict__ W,
                                              const float* __restrict__ bias,
                                              void* __restrict__ outp, int N) {
    __shared__ float Ws[32 * C];
    gemm_body<K, C, TN, BIAS, INBF, OUTBF>(Ap, W, bias, outp, N, blockIdx.x, Ws);
}

// ---------------- fused: gemm1 blocks + fill blocks in one dispatch ----------------
// fill: per edge, rank = atomicAdd(&cnt[dst],1); bucket[rank*N+dst] = src.
// Rank-major bucket: scatter targets are dense 400KB per-rank planes ->
// set-uniform L2 mapping, ~16 writes/line coalesce before writeback.
// 8 edges/thread, independent atomic/store chains for ILP.

__global__ __launch_bounds__(TPB) void fused1_k(const float* __restrict__ x,
                                                const float* __restrict__ W1,
                                                unsigned* __restrict__ h1b,
                                                const int* __restrict__ src,
                                                const int* __restrict__ dst,
                                                int* __restrict__ cnt,
                                                unsigned* __restrict__ bucket,
                                                int N, int E, int gb) {
    __shared__ float Ws[32 * 128];
    if ((int)blockIdx.x < gb) {
        gemm_body<128, 128, 8, false, false, true>(x, W1, nullptr, h1b, N, blockIdx.x, Ws);
    } else {
        int bid = (int)blockIdx.x - gb;
        int e0 = (bid * TPB + (int)threadIdx.x) * 8;
        if (e0 + 7 < E) {
            int4 sa = *(const int4*)&src[e0];
            int4 sb = *(const int4*)&src[e0 + 4];
            int4 da = *(const int4*)&dst[e0];
            int4 db = *(const int4*)&dst[e0 + 4];
            int ss[8] = {sa.x, sa.y, sa.z, sa.w, sb.x, sb.y, sb.z, sb.w};
            int dd[8] = {da.x, da.y, da.z, da.w, db.x, db.y, db.z, db.w};
            int rr[8];
#pragma unroll
            for (int q = 0; q < 8; ++q) rr[q] = atomicAdd(&cnt[dd[q]], 1);
#pragma unroll
            for (int q = 0; q < 8; ++q)
                if (rr[q] < CAP) bucket[(size_t)rr[q] * N + dd[q]] = (unsigned)ss[q];
        } else {
            for (int e = e0; e < E; ++e) {
                int s = src[e], d = dst[e];
                int r = atomicAdd(&cnt[d], 1);
                if (r < CAP) bucket[(size_t)r * N + d] = (unsigned)s;
            }
        }
    }
}

// ---------------- bucket gather aggregation (bf16 rows, on-the-fly coef) ----------------
// h: bf16 [N, 2*F2] viewed as uint [N, F2]; each lane owns 2 features.
// coef = rsqrt(cnt[s]+1) * rsqrt(cnt[n]+1). cnt[s]/entry loads are 64-lane
// broadcasts (1 transaction). Rank-major bucket read: bucket[(j+q)*N+n] --
// same line shared across the block's consecutive nodes. 8-deep unroll.

template <int F2, bool RELU, bool OUTBF>
__global__ __launch_bounds__(TPB) void agg_k(const unsigned* __restrict__ h,
                                             const int* __restrict__ cnt,
                                             const unsigned* __restrict__ bucket,
                                             const float* __restrict__ bias,
                                             void* __restrict__ outp, int N) {
    constexpr int NPB = TPB / F2;
    int ln = threadIdx.x / F2;
    int f2 = threadIdx.x % F2;
    int n  = blockIdx.x * NPB + ln;
    if (n >= N) return;

    int cfull = cnt[n];
    float di = rsqrtf((float)cfull + 1.0f);
    unsigned us = h[(size_t)n * F2 + f2];
    float ax = bf_lo(us) * (di * di);
    float ay = bf_hi(us) * (di * di);

    int cn = cfull < CAP ? cfull : CAP;
    const unsigned* bp = bucket + n;  // rank-major: plane stride = N

    int j = 0;
    for (; j + 7 < cn; j += 8) {
        int s[8], cs[8];
        unsigned v[8];
#pragma unroll
        for (int q = 0; q < 8; ++q) s[q] = (int)bp[(size_t)(j + q) * N];
#pragma unroll
        for (int q = 0; q < 8; ++q) {
            v[q]  = h[(size_t)s[q] * F2 + f2];
            cs[q] = cnt[s[q]];
        }
#pragma unroll
        for (int q = 0; q < 8; ++q) {
            float c = rsqrtf((float)cs[q] + 1.0f) * di;
            ax += c * bf_lo(v[q]);
            ay += c * bf_hi(v[q]);
        }
    }
    for (; j < cn; ++j) {
        int s = (int)bp[(size_t)j * N];
        unsigned v = h[(size_t)s * F2 + f2];
        float c = rsqrtf((float)cnt[s] + 1.0f) * di;
        ax += c * bf_lo(v);
        ay += c * bf_hi(v);
    }

    float rx = ax + bias[2 * f2];
    float ry = ay + bias[2 * f2 + 1];
    if (RELU) { rx = fmaxf(rx, 0.f); ry = fmaxf(ry, 0.f); }
    if (OUTBF) {
        unsigned pk = (unsigned)f2bf(rx) | ((unsigned)f2bf(ry) << 16);
        ((unsigned*)outp)[(size_t)n * F2 + f2] = pk;
    } else {
        v2f r; r.x = rx; r.y = ry;
        __builtin_nontemporal_store(r, (v2f*)outp + (size_t)n * F2 + f2);
    }
}

// ---------------- launch ----------------

extern "C" void kernel_launch(void* const* d_in, const int* in_sizes, int n_in,
                              void* d_out, int out_size, void* d_ws, size_t ws_size,
                              hipStream_t stream) {
    const float* x    = (const float*)d_in[0];
    const int*   eidx = (const int*)d_in[1];
    const float* W1   = (const float*)d_in[2];
    const float* b1   = (const float*)d_in[3];
    const float* W2   = (const float*)d_in[4];
    const float* b2   = (const float*)d_in[5];
    const float* Wd   = (const float*)d_in[6];
    const float* bd   = (const float*)d_in[7];

    const int N = in_sizes[0] / 128;   // 100000
    const int E = in_sizes[1] / 2;     // 1600000
    const int* src = eidx;
    const int* dst = eidx + E;

    size_t off = 0;
    auto alloc = [&](size_t bytes) {
        void* p = (char*)d_ws + off;
        off += (bytes + 255) & ~(size_t)255;
        return p;
    };
    int*      cnt     = (int*)alloc((size_t)N * 4);
    unsigned* bucket  = (unsigned*)alloc((size_t)N * CAP * 4);  // 25.6 MB, rank-major [CAP][N]
    unsigned* h1b     = (unsigned*)alloc((size_t)N * 64 * 4);   // bf16 [N,128]
    unsigned* h2b     = (unsigned*)alloc((size_t)N * 32 * 4);   // bf16 [N,64]
    unsigned* hrelu_b = (unsigned*)alloc((size_t)N * 64 * 4);   // bf16 [N,128]
    (void)ws_size;

    float* x_recon = (float*)d_out;                    // [N,128]
    float* z_out   = (float*)d_out + (size_t)N * 128;  // [N,64]

    const int gb = (N + 127) / 128;                 // 782 gemm blocks
    const int fb = (E + TPB * 8 - 1) / (TPB * 8);   // 782 fill blocks

    (void)hipMemsetAsync(cnt, 0, (size_t)N * 4, stream);

    // fused: gemm1 || (count+fill)
    fused1_k<<<gb + fb, TPB, 0, stream>>>(x, W1, h1b, src, dst, cnt, bucket, N, E, gb);

    // layer 1 aggregation
    agg_k<64, true, true><<<(N + 3) / 4, TPB, 0, stream>>>(h1b, cnt, bucket, b1, hrelu_b, N);
    // layer 2
    gemm_k<128, 64, 4, false, true, true><<<gb, TPB, 0, stream>>>(hrelu_b, W2, nullptr, h2b, N);
    agg_k<32, false, false><<<(N + 7) / 8, TPB, 0, stream>>>(h2b, cnt, bucket, b2, z_out, N);
    // decode
    gemm_k<64, 128, 8, true, false, false><<<gb, TPB, 0, stream>>>(z_out, Wd, bd, x_recon, N);
}

// Round 2
// 473.457 us; speedup vs baseline: 1.0169x; 1.0035x over previous
//
#include <hip/hip_runtime.h>
#include <hip/hip_bf16.h>
#include <hip/hip_fp16.h>

// GCN autoencoder, R7:
//   memset(cnt,binCnt) -> fused1{gemm1(x@W1->bf16 h1) || bin(edges->8 dst-range bins)} ->
//   fill_k(XCD-affine: bin=bid&7 -> cnt atomics + bucket scatter stay in ONE XCD's L2) ->
//   agg1 -> gemm2 -> agg2 -> gemm3
//
// R6 post-mortem: rank-major bucket transpose did NOT reduce WRITE (122->131MB,
// still exactly 64B/edge) -> merging never happens because the 16 writers of any
// bucket line (and ~256 atomic issuers per cnt line) span all 8 XCDs, whose L2s
// are not cross-coherent. Every visit = fetch+writeback at 64B granularity; the
// cnt atomics serialize at the global coherence point (~12 atomics/ns measured).
// R7: partition edges by dst-range into 8 bins (pass A, fused with gemm1), then
// fill with bin = blockIdx.x & 7 (measured round-robin block->XCD mapping, m09).
// All traffic to a given cnt/bucket line now comes from one XCD -> local-L2
// atomics (50KB counters resident) and full write merging (16 writes/line).

#define TPB 256
#define CAP 64
#define BINCAP 220000   // per-bin edge capacity (E/8=200K expected, +48 sigma)
#define FILLW 112       // fill blocks per bin

typedef float v2f __attribute__((ext_vector_type(2)));

// ---------------- helpers ----------------

__device__ __forceinline__ unsigned short f2bf(float f) {
    unsigned u = __float_as_uint(f);
    unsigned r = u + 0x7fffu + ((u >> 16) & 1u);  // RNE
    return (unsigned short)(r >> 16);
}
__device__ __forceinline__ float bf_lo(unsigned u) { return __uint_as_float(u << 16); }
__device__ __forceinline__ float bf_hi(unsigned u) { return __uint_as_float(u & 0xffff0000u); }

// ---------------- GEMM body: out[N,C] = A[N,K] @ W[K,C] (+bias) ----------------

template <int K, int C, int TN, bool BIAS, bool INBF, bool OUTBF>
__device__ __forceinline__ void gemm_body(const void* __restrict__ Ap,
                                          const float* __restrict__ W,
                                          const float* __restrict__ bias,
                                          void* __restrict__ outp, int N, int bid,
                                          float* __restrict__ Ws) {
    constexpr int BM  = 128;
    constexpr int TM  = 8;
    constexpr int BK  = 32;
    constexpr int NCT = C / TN;
    static_assert(NCT * (BM / TM) == TPB, "thread layout");

    int tid = threadIdx.x;
    int tc = tid % NCT;
    int tr = tid / NCT;
    int c0 = tc * TN;
    int r0 = bid * BM + tr * TM;

    float acc[TM][TN] = {};

    for (int k0 = 0; k0 < K; k0 += BK) {
        __syncthreads();
        for (int i = tid * 4; i < BK * C; i += TPB * 4)
            *(float4*)&Ws[i] = *(const float4*)&W[k0 * C + i];
        __syncthreads();

        for (int k = 0; k < BK; k += 4) {
            float4 a[TM];
            uint2  au[TM];
#pragma unroll
            for (int i = 0; i < TM; ++i) {
                int r = r0 + i;
                if (r >= N) r = N - 1;
                if (INBF)
                    au[i] = *(const uint2*)((const unsigned short*)Ap + (size_t)r * K + k0 + k);
                else
                    a[i] = *(const float4*)((const float*)Ap + (size_t)r * K + k0 + k);
            }
#pragma unroll
            for (int kk = 0; kk < 4; ++kk) {
                float w[TN];
#pragma unroll
                for (int j = 0; j < TN; j += 4)
                    *(float4*)&w[j] = *(const float4*)&Ws[(k + kk) * C + c0 + j];
#pragma unroll
                for (int i = 0; i < TM; ++i) {
                    float av;
                    if (INBF) {
                        unsigned uu = (kk < 2) ? au[i].x : au[i].y;
                        av = (kk & 1) ? bf_hi(uu) : bf_lo(uu);
                    } else {
                        av = ((const float*)&a[i])[kk];
                    }
#pragma unroll
                    for (int j = 0; j < TN; ++j) acc[i][j] += av * w[j];
                }
            }
        }
    }

#pragma unroll
    for (int i = 0; i < TM; ++i) {
        int r = r0 + i;
        if (r >= N) continue;
        if (BIAS) {
#pragma unroll
            for (int j = 0; j < TN; ++j) acc[i][j] += bias[c0 + j];
        }
        if (OUTBF) {
            unsigned short* ob = (unsigned short*)outp + (size_t)r * C + c0;
            unsigned pk[TN / 2];
#pragma unroll
            for (int j = 0; j < TN; j += 2)
                pk[j / 2] = (unsigned)f2bf(acc[i][j]) | ((unsigned)f2bf(acc[i][j + 1]) << 16);
            if (TN == 8)      *(uint4*)ob = *(uint4*)pk;
            else if (TN == 4) *(uint2*)ob = *(uint2*)pk;
        } else {
            float* of = (float*)outp + (size_t)r * C + c0;
#pragma unroll
            for (int j = 0; j < TN; j += 4)
                *(float4*)&of[j] = *(float4*)&acc[i][j];
        }
    }
}

// standalone GEMM kernel (layers 2, 3)
template <int K, int C, int TN, bool BIAS, bool INBF, bool OUTBF>
__global__ __launch_bounds__(TPB) void gemm_k(const void* __restrict__ Ap,
                                              const float* __restrict__ W,
                                              const float* __restrict__ bias,
                                              void* __restrict__ outp, int N) {
    __shared__ float Ws[32 * C];
    gemm_body<K, C, TN, BIAS, INBF, OUTBF>(Ap, W, bias, outp, N, blockIdx.x, Ws);
}

// ---------------- fused: gemm1 blocks + edge-binning blocks ----------------
// bin path: per-WG LDS histogram of 8 dst-range bins -> one global atomicAdd
// per (WG,bin) for base offsets (6.3K atomics total) -> scatter (src,dst)
// pairs into per-bin contiguous buffers. Writes are WG-local-contiguous per
// bin (~2KB chunks) -> fully merged in the issuing XCD's L2.
// bin(d) = (d * M) >> 32 with M = floor(2^35 / N): monotone map to [0,8).

__global__ __launch_bounds__(TPB) void fused1_k(const float* __restrict__ x,
                                                const float* __restrict__ W1,
                                                unsigned* __restrict__ h1b,
                                                const int* __restrict__ src,
                                                const int* __restrict__ dst,
                                                uint2* __restrict__ binBuf,
                                                int* __restrict__ binCnt,
                                                int N, int E, int gb, unsigned M) {
    __shared__ float Ws[32 * 128];
    __shared__ int hist[8], gbase[8], lpos[8];
    if ((int)blockIdx.x < gb) {
        gemm_body<128, 128, 8, false, false, true>(x, W1, nullptr, h1b, N, blockIdx.x, Ws);
    } else {
        int bid = (int)blockIdx.x - gb;
        int tid = (int)threadIdx.x;
        if (tid < 8) { hist[tid] = 0; lpos[tid] = 0; }
        __syncthreads();

        int e0 = (bid * TPB + tid) * 8;
        int ne = E - e0; ne = ne > 8 ? 8 : (ne < 0 ? 0 : ne);
        int ss[8], dd[8], bb8[8];
        if (ne == 8) {
            int4 sa = *(const int4*)&src[e0];
            int4 sb = *(const int4*)&src[e0 + 4];
            int4 da = *(const int4*)&dst[e0];
            int4 db = *(const int4*)&dst[e0 + 4];
            ss[0]=sa.x; ss[1]=sa.y; ss[2]=sa.z; ss[3]=sa.w;
            ss[4]=sb.x; ss[5]=sb.y; ss[6]=sb.z; ss[7]=sb.w;
            dd[0]=da.x; dd[1]=da.y; dd[2]=da.z; dd[3]=da.w;
            dd[4]=db.x; dd[5]=db.y; dd[6]=db.z; dd[7]=db.w;
        } else {
            for (int q = 0; q < ne; ++q) { ss[q] = src[e0 + q]; dd[q] = dst[e0 + q]; }
        }
        for (int q = 0; q < ne; ++q) {
            bb8[q] = (int)(((unsigned long long)(unsigned)dd[q] * M) >> 32);
            atomicAdd(&hist[bb8[q]], 1);
        }
        __syncthreads();
        if (tid < 8) gbase[tid] = atomicAdd(&binCnt[tid], hist[tid]);
        __syncthreads();
        for (int q = 0; q < ne; ++q) {
            int b = bb8[q];
            int p = gbase[b] + atomicAdd(&lpos[b], 1);
            if (p < BINCAP)
                binBuf[(size_t)b * BINCAP + p] = make_uint2((unsigned)ss[q], (unsigned)dd[q]);
        }
    }
}

// ---------------- XCD-affine fill ----------------
// bin = blockIdx.x & 7 == XCD id under the measured round-robin dispatch.
// All cnt atomics and bucket stores for a dst-range issue from one XCD:
// cnt lines (50KB/bin) stay resident in that XCD's L2; bucket lines
// (16 same-rank consecutive-d writes) merge before a single writeback.

__global__ __launch_bounds__(TPB) void fill_k(const uint2* __restrict__ binBuf,
                                              const int* __restrict__ binCnt,
                                              int* __restrict__ cnt,
                                              unsigned* __restrict__ bucket, int N) {
    int bin = (int)blockIdx.x & 7;
    int w   = (int)blockIdx.x >> 3;
    int cb  = binCnt[bin];
    if (cb > BINCAP) cb = BINCAP;
    const uint2* eb = binBuf + (size_t)bin * BINCAP;

    for (int base = w * (TPB * 8); base < cb; base += FILLW * (TPB * 8)) {
        int e0 = base + (int)threadIdx.x * 8;
        if (e0 + 8 <= cb) {
            unsigned s[8], d[8];
#pragma unroll
            for (int q = 0; q < 8; q += 2) {
                uint4 t = *(const uint4*)&eb[e0 + q];
                s[q] = t.x; d[q] = t.y; s[q + 1] = t.z; d[q + 1] = t.w;
            }
            int rr[8];
#pragma unroll
            for (int q = 0; q < 8; ++q) rr[q] = atomicAdd(&cnt[(int)d[q]], 1);
#pragma unroll
            for (int q = 0; q < 8; ++q)
                if (rr[q] < CAP) bucket[(size_t)rr[q] * N + d[q]] = s[q];
        } else {
            int lim = e0 + 8 < cb ? e0 + 8 : cb;
            for (int e = e0; e < lim; ++e) {
                uint2 t = eb[e];
                int r = atomicAdd(&cnt[(int)t.y], 1);
                if (r < CAP) bucket[(size_t)r * N + t.y] = t.x;
            }
        }
    }
}

// ---------------- bucket gather aggregation (unchanged from R6) ----------------

template <int F2, bool RELU, bool OUTBF>
__global__ __launch_bounds__(TPB) void agg_k(const unsigned* __restrict__ h,
                                             const int* __restrict__ cnt,
                                             const unsigned* __restrict__ bucket,
                                             const float* __restrict__ bias,
                                             void* __restrict__ outp, int N) {
    constexpr int NPB = TPB / F2;
    int ln = threadIdx.x / F2;
    int f2 = threadIdx.x % F2;
    int n  = blockIdx.x * NPB + ln;
    if (n >= N) return;

    int cfull = cnt[n];
    float di = rsqrtf((float)cfull + 1.0f);
    unsigned us = h[(size_t)n * F2 + f2];
    float ax = bf_lo(us) * (di * di);
    float ay = bf_hi(us) * (di * di);

    int cn = cfull < CAP ? cfull : CAP;
    const unsigned* bp = bucket + n;  // rank-major: plane stride = N

    int j = 0;
    for (; j + 7 < cn; j += 8) {
        int s[8], cs[8];
        unsigned v[8];
#pragma unroll
        for (int q = 0; q < 8; ++q) s[q] = (int)bp[(size_t)(j + q) * N];
#pragma unroll
        for (int q = 0; q < 8; ++q) {
            v[q]  = h[(size_t)s[q] * F2 + f2];
            cs[q] = cnt[s[q]];
        }
#pragma unroll
        for (int q = 0; q < 8; ++q) {
            float c = rsqrtf((float)cs[q] + 1.0f) * di;
            ax += c * bf_lo(v[q]);
            ay += c * bf_hi(v[q]);
        }
    }
    for (; j < cn; ++j) {
        int s = (int)bp[(size_t)j * N];
        unsigned v = h[(size_t)s * F2 + f2];
        float c = rsqrtf((float)cnt[s] + 1.0f) * di;
        ax += c * bf_lo(v);
        ay += c * bf_hi(v);
    }

    float rx = ax + bias[2 * f2];
    float ry = ay + bias[2 * f2 + 1];
    if (RELU) { rx = fmaxf(rx, 0.f); ry = fmaxf(ry, 0.f); }
    if (OUTBF) {
        unsigned pk = (unsigned)f2bf(rx) | ((unsigned)f2bf(ry) << 16);
        ((unsigned*)outp)[(size_t)n * F2 + f2] = pk;
    } else {
        v2f r; r.x = rx; r.y = ry;
        __builtin_nontemporal_store(r, (v2f*)outp + (size_t)n * F2 + f2);
    }
}

// ---------------- launch ----------------

extern "C" void kernel_launch(void* const* d_in, const int* in_sizes, int n_in,
                              void* d_out, int out_size, void* d_ws, size_t ws_size,
                              hipStream_t stream) {
    const float* x    = (const float*)d_in[0];
    const int*   eidx = (const int*)d_in[1];
    const float* W1   = (const float*)d_in[2];
    const float* b1   = (const float*)d_in[3];
    const float* W2   = (const float*)d_in[4];
    const float* b2   = (const float*)d_in[5];
    const float* Wd   = (const float*)d_in[6];
    const float* bd   = (const float*)d_in[7];

    const int N = in_sizes[0] / 128;   // 100000
    const int E = in_sizes[1] / 2;     // 1600000
    const int* src = eidx;
    const int* dst = eidx + E;

    size_t off = 0;
    auto alloc = [&](size_t bytes) {
        void* p = (char*)d_ws + off;
        off += (bytes + 255) & ~(size_t)255;
        return p;
    };
    int*      cnt     = (int*)alloc((size_t)N * 4);
    unsigned* bucket  = (unsigned*)alloc((size_t)N * CAP * 4);  // 25.6 MB, rank-major [CAP][N]
    unsigned* h1b     = (unsigned*)alloc((size_t)N * 64 * 4);   // bf16 [N,128]
    unsigned* h2b     = (unsigned*)alloc((size_t)N * 32 * 4);   // bf16 [N,64]
    unsigned* hrelu_b = (unsigned*)alloc((size_t)N * 64 * 4);   // bf16 [N,128]
    int*      binCnt  = (int*)alloc(256);
    // binBuf (8*BINCAP*8B = 14.1MB) overlays hrelu_b: dead before agg1 writes it.
    uint2*    binBuf  = (uint2*)hrelu_b;
    (void)ws_size;

    float* x_recon = (float*)d_out;                    // [N,128]
    float* z_out   = (float*)d_out + (size_t)N * 128;  // [N,64]

    const int gb = (N + 127) / 128;                 // 782 gemm blocks
    const int bb = (E + TPB * 8 - 1) / (TPB * 8);   // 782 bin blocks
    const unsigned M = (unsigned)((8ULL << 32) / (unsigned)N);  // bin multiplier

    (void)hipMemsetAsync(cnt, 0, (size_t)N * 4, stream);
    (void)hipMemsetAsync(binCnt, 0, 256, stream);

    // fused: gemm1 || edge binning
    fused1_k<<<gb + bb, TPB, 0, stream>>>(x, W1, h1b, src, dst, binBuf, binCnt, N, E, gb, M);
    // XCD-affine count+fill
    fill_k<<<8 * FILLW, TPB, 0, stream>>>(binBuf, binCnt, cnt, bucket, N);

    // layer 1 aggregation
    agg_k<64, true, true><<<(N + 3) / 4, TPB, 0, stream>>>(h1b, cnt, bucket, b1, hrelu_b, N);
    // layer 2
    gemm_k<128, 64, 4, false, true, true><<<gb, TPB, 0, stream>>>(hrelu_b, W2, nullptr, h2b, N);
    agg_k<32, false, false><<<(N + 7) / 8, TPB, 0, stream>>>(h2b, cnt, bucket, b2, z_out, N);
    // decode
    gemm_k<64, 128, 8, true, false, false><<<gb, TPB, 0, stream>>>(z_out, Wd, bd, x_recon, N);
}

// Round 3
// 470.171 us; speedup vs baseline: 1.0240x; 1.0070x over previous
//
#include <hip/hip_runtime.h>
#include <hip/hip_bf16.h>
#include <hip/hip_fp16.h>

// GCN autoencoder, R8:
//   memset -> fused1{gemm1 || bin} -> fill_k(XCD-affine) -> dinv_k ->
//   agg1(dinv-table, prefetched, packed-fma) -> gemm2 -> agg2 -> gemm3
//
// R7 post-mortem: fill fixed (fused1 160us -> out of top-5). New hog: agg_k L1
// at 87us, FETCH 223MB = 8 XCDs x 25.6MB table -- structural L2 replication of
// the random gather (LLC-absorbed, not HBM). 2.9TB/s with VALUBusy 64% -> NOT
// proven BW-bound; per-edge VALU waste: rsqrt (transcendental) + cvt per edge,
// scalar FMAs, serialized bucket->gather latency chain.
// R8: (1) dinv[] table precomputed once (L2-resident, replaces rsqrt+cvt+add);
// (2) software-prefetch next bucket chunk across current chunk's math;
// (3) packed v2f accumulate (v_pk_fma_f32) + per-lane base pointer.
// Numerics bit-identical (dinv computed with same rsqrtf).
// Falsifier: if agg1 stays ~87us at 2.9TB/s -> MALL ceiling -> R9 = fp8 tables.

#define TPB 256
#define CAP 64
#define BINCAP 220000   // per-bin edge capacity (E/8=200K expected)
#define FILLW 112       // fill blocks per bin

typedef float v2f __attribute__((ext_vector_type(2)));

// ---------------- helpers ----------------

__device__ __forceinline__ unsigned short f2bf(float f) {
    unsigned u = __float_as_uint(f);
    unsigned r = u + 0x7fffu + ((u >> 16) & 1u);  // RNE
    return (unsigned short)(r >> 16);
}
__device__ __forceinline__ float bf_lo(unsigned u) { return __uint_as_float(u << 16); }
__device__ __forceinline__ float bf_hi(unsigned u) { return __uint_as_float(u & 0xffff0000u); }

// ---------------- GEMM body: out[N,C] = A[N,K] @ W[K,C] (+bias) ----------------

template <int K, int C, int TN, bool BIAS, bool INBF, bool OUTBF>
__device__ __forceinline__ void gemm_body(const void* __restrict__ Ap,
                                          const float* __restrict__ W,
                                          const float* __restrict__ bias,
                                          void* __restrict__ outp, int N, int bid,
                                          float* __restrict__ Ws) {
    constexpr int BM  = 128;
    constexpr int TM  = 8;
    constexpr int BK  = 32;
    constexpr int NCT = C / TN;
    static_assert(NCT * (BM / TM) == TPB, "thread layout");

    int tid = threadIdx.x;
    int tc = tid % NCT;
    int tr = tid / NCT;
    int c0 = tc * TN;
    int r0 = bid * BM + tr * TM;

    float acc[TM][TN] = {};

    for (int k0 = 0; k0 < K; k0 += BK) {
        __syncthreads();
        for (int i = tid * 4; i < BK * C; i += TPB * 4)
            *(float4*)&Ws[i] = *(const float4*)&W[k0 * C + i];
        __syncthreads();

        for (int k = 0; k < BK; k += 4) {
            float4 a[TM];
            uint2  au[TM];
#pragma unroll
            for (int i = 0; i < TM; ++i) {
                int r = r0 + i;
                if (r >= N) r = N - 1;
                if (INBF)
                    au[i] = *(const uint2*)((const unsigned short*)Ap + (size_t)r * K + k0 + k);
                else
                    a[i] = *(const float4*)((const float*)Ap + (size_t)r * K + k0 + k);
            }
#pragma unroll
            for (int kk = 0; kk < 4; ++kk) {
                float w[TN];
#pragma unroll
                for (int j = 0; j < TN; j += 4)
                    *(float4*)&w[j] = *(const float4*)&Ws[(k + kk) * C + c0 + j];
#pragma unroll
                for (int i = 0; i < TM; ++i) {
                    float av;
                    if (INBF) {
                        unsigned uu = (kk < 2) ? au[i].x : au[i].y;
                        av = (kk & 1) ? bf_hi(uu) : bf_lo(uu);
                    } else {
                        av = ((const float*)&a[i])[kk];
                    }
#pragma unroll
                    for (int j = 0; j < TN; ++j) acc[i][j] += av * w[j];
                }
            }
        }
    }

#pragma unroll
    for (int i = 0; i < TM; ++i) {
        int r = r0 + i;
        if (r >= N) continue;
        if (BIAS) {
#pragma unroll
            for (int j = 0; j < TN; ++j) acc[i][j] += bias[c0 + j];
        }
        if (OUTBF) {
            unsigned short* ob = (unsigned short*)outp + (size_t)r * C + c0;
            unsigned pk[TN / 2];
#pragma unroll
            for (int j = 0; j < TN; j += 2)
                pk[j / 2] = (unsigned)f2bf(acc[i][j]) | ((unsigned)f2bf(acc[i][j + 1]) << 16);
            if (TN == 8)      *(uint4*)ob = *(uint4*)pk;
            else if (TN == 4) *(uint2*)ob = *(uint2*)pk;
        } else {
            float* of = (float*)outp + (size_t)r * C + c0;
#pragma unroll
            for (int j = 0; j < TN; j += 4)
                *(float4*)&of[j] = *(float4*)&acc[i][j];
        }
    }
}

// standalone GEMM kernel (layers 2, 3)
template <int K, int C, int TN, bool BIAS, bool INBF, bool OUTBF>
__global__ __launch_bounds__(TPB) void gemm_k(const void* __restrict__ Ap,
                                              const float* __restrict__ W,
                                              const float* __restrict__ bias,
                                              void* __restrict__ outp, int N) {
    __shared__ float Ws[32 * C];
    gemm_body<K, C, TN, BIAS, INBF, OUTBF>(Ap, W, bias, outp, N, blockIdx.x, Ws);
}

// ---------------- fused: gemm1 blocks + edge-binning blocks ----------------

__global__ __launch_bounds__(TPB) void fused1_k(const float* __restrict__ x,
                                                const float* __restrict__ W1,
                                                unsigned* __restrict__ h1b,
                                                const int* __restrict__ src,
                                                const int* __restrict__ dst,
                                                uint2* __restrict__ binBuf,
                                                int* __restrict__ binCnt,
                                                int N, int E, int gb, unsigned M) {
    __shared__ float Ws[32 * 128];
    __shared__ int hist[8], gbase[8], lpos[8];
    if ((int)blockIdx.x < gb) {
        gemm_body<128, 128, 8, false, false, true>(x, W1, nullptr, h1b, N, blockIdx.x, Ws);
    } else {
        int bid = (int)blockIdx.x - gb;
        int tid = (int)threadIdx.x;
        if (tid < 8) { hist[tid] = 0; lpos[tid] = 0; }
        __syncthreads();

        int e0 = (bid * TPB + tid) * 8;
        int ne = E - e0; ne = ne > 8 ? 8 : (ne < 0 ? 0 : ne);
        int ss[8], dd[8], bb8[8];
        if (ne == 8) {
            int4 sa = *(const int4*)&src[e0];
            int4 sb = *(const int4*)&src[e0 + 4];
            int4 da = *(const int4*)&dst[e0];
            int4 db = *(const int4*)&dst[e0 + 4];
            ss[0]=sa.x; ss[1]=sa.y; ss[2]=sa.z; ss[3]=sa.w;
            ss[4]=sb.x; ss[5]=sb.y; ss[6]=sb.z; ss[7]=sb.w;
            dd[0]=da.x; dd[1]=da.y; dd[2]=da.z; dd[3]=da.w;
            dd[4]=db.x; dd[5]=db.y; dd[6]=db.z; dd[7]=db.w;
        } else {
            for (int q = 0; q < ne; ++q) { ss[q] = src[e0 + q]; dd[q] = dst[e0 + q]; }
        }
        for (int q = 0; q < ne; ++q) {
            bb8[q] = (int)(((unsigned long long)(unsigned)dd[q] * M) >> 32);
            atomicAdd(&hist[bb8[q]], 1);
        }
        __syncthreads();
        if (tid < 8) gbase[tid] = atomicAdd(&binCnt[tid], hist[tid]);
        __syncthreads();
        for (int q = 0; q < ne; ++q) {
            int b = bb8[q];
            int p = gbase[b] + atomicAdd(&lpos[b], 1);
            if (p < BINCAP)
                binBuf[(size_t)b * BINCAP + p] = make_uint2((unsigned)ss[q], (unsigned)dd[q]);
        }
    }
}

// ---------------- XCD-affine fill ----------------

__global__ __launch_bounds__(TPB) void fill_k(const uint2* __restrict__ binBuf,
                                              const int* __restrict__ binCnt,
                                              int* __restrict__ cnt,
                                              unsigned* __restrict__ bucket, int N) {
    int bin = (int)blockIdx.x & 7;
    int w   = (int)blockIdx.x >> 3;
    int cb  = binCnt[bin];
    if (cb > BINCAP) cb = BINCAP;
    const uint2* eb = binBuf + (size_t)bin * BINCAP;

    for (int base = w * (TPB * 8); base < cb; base += FILLW * (TPB * 8)) {
        int e0 = base + (int)threadIdx.x * 8;
        if (e0 + 8 <= cb) {
            unsigned s[8], d[8];
#pragma unroll
            for (int q = 0; q < 8; q += 2) {
                uint4 t = *(const uint4*)&eb[e0 + q];
                s[q] = t.x; d[q] = t.y; s[q + 1] = t.z; d[q + 1] = t.w;
            }
            int rr[8];
#pragma unroll
            for (int q = 0; q < 8; ++q) rr[q] = atomicAdd(&cnt[(int)d[q]], 1);
#pragma unroll
            for (int q = 0; q < 8; ++q)
                if (rr[q] < CAP) bucket[(size_t)rr[q] * N + d[q]] = s[q];
        } else {
            int lim = e0 + 8 < cb ? e0 + 8 : cb;
            for (int e = e0; e < lim; ++e) {
                uint2 t = eb[e];
                int r = atomicAdd(&cnt[(int)t.y], 1);
                if (r < CAP) bucket[(size_t)r * N + t.y] = t.x;
            }
        }
    }
}

// ---------------- dinv precompute: dinv[n] = rsqrt(cnt[n]+1) ----------------
// 400KB table, L2-resident. Same rsqrtf as before -> bit-identical numerics.

__global__ __launch_bounds__(TPB) void dinv_k(const int* __restrict__ cnt,
                                              float* __restrict__ dinv, int N) {
    int i = blockIdx.x * TPB + (int)threadIdx.x;
    if (i < N) dinv[i] = rsqrtf((float)cnt[i] + 1.0f);
}

// ---------------- bucket gather aggregation ----------------
// dinv-table coef (no transcendental in the loop), next-chunk bucket prefetch,
// packed v2f accumulate, per-lane base pointer.

template <int F2, bool RELU, bool OUTBF>
__global__ __launch_bounds__(TPB) void agg_k(const unsigned* __restrict__ h,
                                             const float* __restrict__ dinv,
                                             const int* __restrict__ cnt,
                                             const unsigned* __restrict__ bucket,
                                             const float* __restrict__ bias,
                                             void* __restrict__ outp, int N) {
    constexpr int NPB = TPB / F2;
    int ln = threadIdx.x / F2;
    int f2 = threadIdx.x % F2;
    int n  = blockIdx.x * NPB + ln;
    if (n >= N) return;

    int cfull = cnt[n];
    float di = dinv[n];
    const unsigned* hp = h + f2;
    unsigned us = hp[(size_t)n * F2];
    v2f acc;
    acc.x = bf_lo(us) * (di * di);
    acc.y = bf_hi(us) * (di * di);

    int cn = cfull < CAP ? cfull : CAP;
    const unsigned* bp = bucket + n;  // rank-major: plane stride = N

    int nfull = cn & ~7;
    int s[8], sn2[8];
    if (nfull > 0) {
#pragma unroll
        for (int q = 0; q < 8; ++q) s[q] = (int)bp[(size_t)q * N];
    }
    for (int j = 0; j < nfull; ) {
        int jn = j + 8;
        bool more = jn < nfull;
        if (more) {
#pragma unroll
            for (int q = 0; q < 8; ++q) sn2[q] = (int)bp[(size_t)(jn + q) * N];
        }
        unsigned v[8];
        float ds[8];
#pragma unroll
        for (int q = 0; q < 8; ++q) {
            v[q]  = hp[(size_t)s[q] * F2];
            ds[q] = dinv[s[q]];
        }
#pragma unroll
        for (int q = 0; q < 8; ++q) {
            float c = ds[q] * di;
            v2f hv; hv.x = bf_lo(v[q]); hv.y = bf_hi(v[q]);
            acc += hv * c;
        }
        if (more) {
#pragma unroll
            for (int q = 0; q < 8; ++q) s[q] = sn2[q];
        }
        j = jn;
    }
    for (int j = nfull; j < cn; ++j) {
        int sx = (int)bp[(size_t)j * N];
        unsigned v = hp[(size_t)sx * F2];
        float c = dinv[sx] * di;
        acc.x += c * bf_lo(v);
        acc.y += c * bf_hi(v);
    }

    float rx = acc.x + bias[2 * f2];
    float ry = acc.y + bias[2 * f2 + 1];
    if (RELU) { rx = fmaxf(rx, 0.f); ry = fmaxf(ry, 0.f); }
    if (OUTBF) {
        unsigned pk = (unsigned)f2bf(rx) | ((unsigned)f2bf(ry) << 16);
        ((unsigned*)outp)[(size_t)n * F2 + f2] = pk;
    } else {
        v2f r; r.x = rx; r.y = ry;
        __builtin_nontemporal_store(r, (v2f*)outp + (size_t)n * F2 + f2);
    }
}

// ---------------- launch ----------------

extern "C" void kernel_launch(void* const* d_in, const int* in_sizes, int n_in,
                              void* d_out, int out_size, void* d_ws, size_t ws_size,
                              hipStream_t stream) {
    const float* x    = (const float*)d_in[0];
    const int*   eidx = (const int*)d_in[1];
    const float* W1   = (const float*)d_in[2];
    const float* b1   = (const float*)d_in[3];
    const float* W2   = (const float*)d_in[4];
    const float* b2   = (const float*)d_in[5];
    const float* Wd   = (const float*)d_in[6];
    const float* bd   = (const float*)d_in[7];

    const int N = in_sizes[0] / 128;   // 100000
    const int E = in_sizes[1] / 2;     // 1600000
    const int* src = eidx;
    const int* dst = eidx + E;

    size_t off = 0;
    auto alloc = [&](size_t bytes) {
        void* p = (char*)d_ws + off;
        off += (bytes + 255) & ~(size_t)255;
        return p;
    };
    int*      cnt     = (int*)alloc((size_t)N * 4);
    float*    dinv    = (float*)alloc((size_t)N * 4);
    unsigned* bucket  = (unsigned*)alloc((size_t)N * CAP * 4);  // 25.6 MB, rank-major [CAP][N]
    unsigned* h1b     = (unsigned*)alloc((size_t)N * 64 * 4);   // bf16 [N,128]
    unsigned* h2b     = (unsigned*)alloc((size_t)N * 32 * 4);   // bf16 [N,64]
    unsigned* hrelu_b = (unsigned*)alloc((size_t)N * 64 * 4);   // bf16 [N,128]
    int*      binCnt  = (int*)alloc(256);
    // binBuf (8*BINCAP*8B = 14.1MB) overlays hrelu_b: dead before agg1 writes it.
    uint2*    binBuf  = (uint2*)hrelu_b;
    (void)ws_size;

    float* x_recon = (float*)d_out;                    // [N,128]
    float* z_out   = (float*)d_out + (size_t)N * 128;  // [N,64]

    const int gb = (N + 127) / 128;                 // 782 gemm blocks
    const int bb = (E + TPB * 8 - 1) / (TPB * 8);   // 782 bin blocks
    const unsigned M = (unsigned)((8ULL << 32) / (unsigned)N);  // bin multiplier

    (void)hipMemsetAsync(cnt, 0, (size_t)N * 4, stream);
    (void)hipMemsetAsync(binCnt, 0, 256, stream);

    // fused: gemm1 || edge binning
    fused1_k<<<gb + bb, TPB, 0, stream>>>(x, W1, h1b, src, dst, binBuf, binCnt, N, E, gb, M);
    // XCD-affine count+fill
    fill_k<<<8 * FILLW, TPB, 0, stream>>>(binBuf, binCnt, cnt, bucket, N);
    // dinv table
    dinv_k<<<(N + TPB - 1) / TPB, TPB, 0, stream>>>(cnt, dinv, N);

    // layer 1 aggregation
    agg_k<64, true, true><<<(N + 3) / 4, TPB, 0, stream>>>(h1b, dinv, cnt, bucket, b1, hrelu_b, N);
    // layer 2
    gemm_k<128, 64, 4, false, true, true><<<gb, TPB, 0, stream>>>(hrelu_b, W2, nullptr, h2b, N);
    agg_k<32, false, false><<<(N + 7) / 8, TPB, 0, stream>>>(h2b, dinv, cnt, bucket, b2, z_out, N);
    // decode
    gemm_k<64, 128, 8, true, false, false><<<gb, TPB, 0, stream>>>(z_out, Wd, bd, x_recon, N);
}